// Round 2
// baseline (79.180 us; speedup 1.0000x reference)
//
#include <hip/hip_runtime.h>
#include <math.h>

// Problem constants (from reference)
#define NPTS   30929          // total points across 5 levels
#define BATCH  4
#define NGT    64             // M gt boxes per batch
#define BN     (BATCH * NPTS) // 123716 rows per output tensor
#define INF_F  1e8f

// Level tables: offsets {0,23200,29000,30450,30825,30929}
// widths {200,100,50,25,13}, strides {8,16,32,64,128}
// regress ranges {(-1,48),(48,96),(96,192),(192,384),(384,1e8)}

__global__ __launch_bounds__(256)
void fcos3d_target_kernel(const float* __restrict__ gt_bboxes,    // (B,M,4)
                          const float* __restrict__ gt_bboxes_3d, // (B,M,9)
                          const int*   __restrict__ gt_labels_3d, // (B,M)
                          const float* __restrict__ centers2d,    // (B,M,2)
                          const float* __restrict__ depths,       // (B,M)
                          const int*   __restrict__ attr_labels,  // (B,M)
                          float* __restrict__ out)
{
#pragma clang fp contract(off)
    const int b = blockIdx.y;
    const int p = blockIdx.x * blockDim.x + threadIdx.x;
    if (p >= NPTS) return;

    // Level lookup (branchless selects; no dynamically-indexed private arrays)
    const int   lvl    = (p >= 23200) + (p >= 29000) + (p >= 30450) + (p >= 30825);
    const int   off    = (lvl == 0) ? 0 : (lvl == 1) ? 23200 : (lvl == 2) ? 29000
                        : (lvl == 3) ? 30450 : 30825;
    const int   n_lvl  = (lvl == 0) ? 23200 : (lvl == 1) ? 5800 : (lvl == 2) ? 1450
                        : (lvl == 3) ? 375 : 104;
    const int   w      = (lvl == 0) ? 200 : (lvl == 1) ? 100 : (lvl == 2) ? 50
                        : (lvl == 3) ? 25 : 13;
    const float stride = (float)(8 << lvl);
    const float rr0    = (lvl == 0) ? -1.f : (lvl == 1) ? 48.f : (lvl == 2) ? 96.f
                        : (lvl == 3) ? 192.f : 384.f;
    const float rr1    = (lvl == 0) ? 48.f : (lvl == 1) ? 96.f : (lvl == 2) ? 192.f
                        : (lvl == 3) ? 384.f : 1e8f;

    const int   pl  = p - off;
    const int   row = pl / w;
    const int   col = pl - row * w;
    const float x   = (float)col * stride + 0.5f * stride;
    const float y   = (float)row * stride + 0.5f * stride;
    const float r   = stride * 1.5f;   // RADIUS = 1.5

    // Wave-uniform GT bases -> compiler emits scalar (s_load) reads
    const float2* __restrict__ c2  = (const float2*)centers2d + (size_t)b * NGT;
    const float4* __restrict__ gbb = (const float4*)gt_bboxes + (size_t)b * NGT;

    // Argmin over masked distances (first-occurrence semantics: strict <)
    float best = INF_F;
    int   ind  = 0;
    #pragma unroll 8
    for (int m = 0; m < NGT; ++m) {
        const float2 c  = c2[m];   // uniform -> scalar load
        const float4 bb = gbb[m];  // uniform -> scalar load
        const float dx = x - c.x;
        const float dy = y - c.y;
        const float left   = x - bb.x;
        const float top    = y - bb.y;
        const float right  = bb.z - x;
        const float bottom = bb.w - y;
        const float mrd = fmaxf(fmaxf(left, top), fmaxf(right, bottom));
        const float cb1 = fminf(x - (c.x - r), (c.x + r) - x);
        const float cb2 = fminf(y - (c.y - r), (c.y + r) - y);
        const float cbm = fminf(cb1, cb2);
        const bool cond = (cbm > 0.f) && (mrd >= rr0) && (mrd <= rr1);
        const float d = cond ? sqrtf(dx * dx + dy * dy) : INF_F;
        if (d < best) { best = d; ind = m; }
    }
    const bool bg = (best >= INF_F);
    const int  gi = b * NGT + ind;

    const int label = bg ? 10 : gt_labels_3d[gi];  // NUM_CLASSES = 10
    const int attr  = bg ? 9  : attr_labels[gi];   // NUM_ATTRS = 9

    // Gather targets from the selected box (even for background, like the ref)
    const float2 cw = c2[ind];
    const float dx = x - cw.x;
    const float dy = y - cw.y;
    const float depth = depths[gi];
    const float g0 = gt_bboxes_3d[gi * 9 + 0];
    const float g2 = gt_bboxes_3d[gi * 9 + 2];
    const float g6 = gt_bboxes_3d[gi * 9 + 6];
    const float yaw = -atan2f(g0, g2) + g6;

    // centerness: exp(-ALPHA * sqrt(dx^2+dy^2) / (1.414 * stride * RADIUS))
    const float rel  = sqrtf(dx * dx + dy * dy) / (1.414f * stride * 1.5f);
    const float cent = expf(-2.5f * rel);

    // Output index: levels concatenated, batch-major within level
    const int gidx = BATCH * off + b * n_lvl + pl;

    // Output layout: [labels(BN)] [bt3d(BN,9)] [centerness(BN)] [attr(BN)]
    out[gidx] = (float)label;
    float* bo = out + BN + (size_t)gidx * 9;
    bo[0] = dx / stride;
    bo[1] = dy / stride;
    bo[2] = depth;
    bo[3] = gt_bboxes_3d[gi * 9 + 3];
    bo[4] = gt_bboxes_3d[gi * 9 + 4];
    bo[5] = gt_bboxes_3d[gi * 9 + 5];
    bo[6] = yaw;
    bo[7] = gt_bboxes_3d[gi * 9 + 7];
    bo[8] = gt_bboxes_3d[gi * 9 + 8];
    out[(size_t)BN * 10 + gidx] = cent;
    out[(size_t)BN * 11 + gidx] = (float)attr;
}

extern "C" void kernel_launch(void* const* d_in, const int* in_sizes, int n_in,
                              void* d_out, int out_size, void* d_ws, size_t ws_size,
                              hipStream_t stream) {
    // setup_inputs() order:
    // 0: gt_bboxes (B,M,4) f32      1: gt_labels (B,M) i32 [unused]
    // 2: gt_bboxes_3d (B,M,9) f32   3: gt_labels_3d (B,M) i32
    // 4: centers2d (B,M,2) f32      5: depths (B,M) f32
    // 6: attr_labels (B,M) i32
    const float* gt_bboxes    = (const float*)d_in[0];
    const float* gt_bboxes_3d = (const float*)d_in[2];
    const int*   gt_labels_3d = (const int*)d_in[3];
    const float* centers2d    = (const float*)d_in[4];
    const float* depths       = (const float*)d_in[5];
    const int*   attr_labels  = (const int*)d_in[6];
    float* out = (float*)d_out;

    dim3 grid((NPTS + 255) / 256, BATCH);
    fcos3d_target_kernel<<<grid, 256, 0, stream>>>(
        gt_bboxes, gt_bboxes_3d, gt_labels_3d, centers2d, depths, attr_labels, out);
}